// Round 13
// baseline (551.603 us; speedup 1.0000x reference)
//
#include <hip/hip_runtime.h>
#include <hip/hip_bf16.h>

#define N_NODES 10000
#define N_EDGES 160000
#define HID 300
#define HIDP 304
#define NPARTB (N_EDGES - N_NODES)   // 150000
#define KS 328                        // H-plane k-stride in shorts
#define RBM 80                        // mega rows/block (5 M-tiles); exact 1875
#define RBF 32                        // fuse rows/block (2 M-tiles)
#define PARTB_BLOCKS 1875             // 150000/80 exact
#define GEMMA_BLOCKS 125              // 10000/80 exact
#define FILL_BLOCKS 313               // ceil(160000/512)
#define MEGA_BLOCKS (PARTB_BLOCKS + GEMMA_BLOCKS + FILL_BLOCKS)
#define FUSE_BLOCKS 313               // ceil(10000/32)

typedef __attribute__((ext_vector_type(8))) short short8;
typedef __attribute__((ext_vector_type(4))) float f32x4;

#define MFMA_B16(a, b, c) __builtin_amdgcn_mfma_f32_16x16x32_bf16(a, b, c, 0, 0, 0)

__device__ __forceinline__ short bf16r(float x) {
    unsigned u = __float_as_uint(x);
    return (short)((u + 0x7fffu + ((u >> 16) & 1u)) >> 16);
}
__device__ __forceinline__ float b2f(unsigned short u) {
    return __uint_as_float(((unsigned)u) << 16);
}
__device__ __forceinline__ void split1(float x, short& hi, short& lo) {
    short h = bf16r(x);
    float hf = __uint_as_float(((unsigned)(unsigned short)h) << 16);
    hi = h;
    lo = bf16r(x - hf);
}

// ---------------------------------------------------------------------------
// k_prep: weight pre-split (layout verified R2-R12) + degree count.
// ---------------------------------------------------------------------------
__global__ void k_prep(const float* __restrict__ g0w, const float* __restrict__ gw,
                       short* __restrict__ wt0, short* __restrict__ wtl,
                       const int* __restrict__ col, int* __restrict__ cnt) {
    int idx = blockIdx.x * 256 + threadIdx.x;
    if (idx < N_EDGES) atomicAdd(&cnt[col[idx]], 1);
    if (idx < 1216) {
        int n16 = idx & 15, q = (idx >> 4) & 3, nt = idx >> 6;
        int n = nt * 16 + n16;
        short* hd = wt0 + (size_t)(nt * 8 + q) * 128 + n16 * 8;
        short* ld = wt0 + (size_t)(nt * 8 + 4 + q) * 128 + n16 * 8;
#pragma unroll
        for (int j = 0; j < 8; ++j) {
            int k = q * 8 + j;
            float f = (n < HID) ? g0w[k * HID + n] : 0.0f;
            short hi, lo;
            split1(f, hi, lo);
            hd[j] = hi;
            ld[j] = lo;
        }
    } else if (idx < 1216 + 48640) {
        int i = idx - 1216;
        int n16 = i & 15; i >>= 4;
        int q = i & 3; i >>= 2;
        int nt = i % 19; i /= 19;
        int chunk = i % 10;
        int l = i / 10;
        int n = nt * 16 + n16;
        int cnt_idx = chunk * 19 + nt;
        short* base = wtl + (size_t)l * 194560;
        short* hd = base + (size_t)(cnt_idx * 8 + q) * 128 + n16 * 8;
        short* ld = base + (size_t)(cnt_idx * 8 + 4 + q) * 128 + n16 * 8;
#pragma unroll
        for (int j = 0; j < 8; ++j) {
            int k = chunk * 32 + q * 8 + j;
            float f = (k < HID && n < HID) ? gw[((size_t)l * HID + k) * HID + n] : 0.0f;
            short hi, lo;
            split1(f, hi, lo);
            hd[j] = hi;
            ld[j] = lo;
        }
    }
}

// k_scan: 1024 threads, 10 iterations (R10-R12 verified)
__global__ __launch_bounds__(1024) void k_scan(
    const int* __restrict__ cnt, int* __restrict__ col_start,
    int* __restrict__ cursor, float* __restrict__ dinv,
    float* __restrict__ selfnorm) {
    __shared__ int wsum[16];
    int t = threadIdx.x;
    int lane = t & 63, w = t >> 6;
    int carry = 0;
    for (int base = 0; base < N_NODES; base += 1024) {
        int i = base + t;
        int v = (i < N_NODES) ? cnt[i] : 0;
        int s = v;
#pragma unroll
        for (int d = 1; d < 64; d <<= 1) {
            int n = __shfl_up(s, d, 64);
            if (lane >= d) s += n;
        }
        if (lane == 63) wsum[w] = s;
        __syncthreads();
        int woff = 0, total = 0;
#pragma unroll
        for (int k = 0; k < 16; ++k) {
            if (k < w) woff += wsum[k];
            total += wsum[k];
        }
        if (i < N_NODES) {
            int excl = carry + woff + s - v;
            col_start[i] = excl;
            cursor[i] = excl;
            float dd = (float)v + 1.0f;
            dinv[i] = rsqrtf(dd);
            selfnorm[i] = 1.0f / dd;
        }
        carry += total;
        __syncthreads();
    }
    if (t == 0) col_start[N_NODES] = carry;
}

// ---------------------------------------------------------------------------
// GCN core (verified R9-R12): MT 16-row tiles/wave, NTC n-tiles, 2-term
// split-bf16, runtime chunk loop (unroll 1 — spill lesson), single-buffered.
// ---------------------------------------------------------------------------
template <int MT, int NTC>
__device__ __forceinline__ void kloop(const short* __restrict__ wp, int nch,
                                      const short* Hh, int nt0, int quad, int l16,
                                      f32x4 (&acc)[MT][NTC]) {
#pragma unroll
    for (int mt = 0; mt < MT; ++mt)
#pragma unroll
        for (int i = 0; i < NTC; ++i)
#pragma unroll
            for (int r = 0; r < 4; ++r) acc[mt][i][r] = 0.0f;
#pragma unroll 1
    for (int c = 0; c < nch; ++c) {
        const short* cb = wp + (size_t)(c * 19 + nt0) * 1024 + quad * 128 + l16 * 8;
        short8 ah[MT];
#pragma unroll
        for (int mt = 0; mt < MT; ++mt)
            ah[mt] = *(const short8*)&Hh[(mt * 16 + l16) * KS + c * 32 + quad * 8];
        short8 bb[NTC];
#pragma unroll
        for (int i = 0; i < NTC; ++i) bb[i] = *(const short8*)(cb + (size_t)i * 1024);
#pragma unroll
        for (int mt = 0; mt < MT; ++mt)
#pragma unroll
            for (int i = 0; i < NTC; ++i)
                acc[mt][i] = MFMA_B16(ah[mt], bb[i], acc[mt][i]);
#pragma unroll
        for (int i = 0; i < NTC; ++i) bb[i] = *(const short8*)(cb + (size_t)i * 1024 + 512);
#pragma unroll
        for (int mt = 0; mt < MT; ++mt)
#pragma unroll
            for (int i = 0; i < NTC; ++i)
                acc[mt][i] = MFMA_B16(ah[mt], bb[i], acc[mt][i]);
    }
}

template <int MT, int NTC>
__device__ __forceinline__ void gcn_epilogue(const float* __restrict__ bias,
                                             int nt0, int quad, int l16,
                                             f32x4 (&acc)[MT][NTC], short* Hh) {
#pragma unroll
    for (int i = 0; i < NTC; ++i) {
        int c = (nt0 + i) * 16 + l16;
        float b = (c < HID) ? bias[c] : 0.0f;
#pragma unroll
        for (int mt = 0; mt < MT; ++mt)
#pragma unroll
            for (int r = 0; r < 4; ++r) {
                float v = fmaxf(acc[mt][i][r] + b, 0.0f);
                Hh[(mt * 16 + quad * 4 + r) * KS + c] = bf16r(v);
            }
    }
}

// final partB layer: column sums -> PLAIN per-block store (R10-R12 fix)
template <int MT, int NTC>
__device__ __forceinline__ void gcn_final(const float* __restrict__ bias,
                                          int nt0, int quad, int l16,
                                          f32x4 (&acc)[MT][NTC],
                                          float* __restrict__ gout) {
#pragma unroll
    for (int i = 0; i < NTC; ++i) {
        int c = (nt0 + i) * 16 + l16;
        float b = (c < HID) ? bias[c] : 0.0f;
        float s = 0.0f;
#pragma unroll
        for (int mt = 0; mt < MT; ++mt)
#pragma unroll
            for (int r = 0; r < 4; ++r) s += fmaxf(acc[mt][i][r] + b, 0.0f);
        s += __shfl_xor(s, 16, 64);
        s += __shfl_xor(s, 32, 64);
        if (quad == 0) gout[c] = (c < HID) ? s : 0.0f;
    }
}

template <int MT, int NTC>
__device__ __forceinline__ void gemm_out(int base, int nt0, int quad, int l16,
                                         f32x4 (&acc)[MT][NTC],
                                         unsigned short* __restrict__ HW) {
#pragma unroll
    for (int i = 0; i < NTC; ++i) {
        int c = (nt0 + i) * 16 + l16;
#pragma unroll
        for (int mt = 0; mt < MT; ++mt)
#pragma unroll
            for (int r = 0; r < 4; ++r) {
                int gm = base + mt * 16 + quad * 4 + r;
                if (gm < N_NODES)
                    HW[(size_t)gm * HIDP + c] = (unsigned short)bf16r(acc[mt][i][r]);
            }
    }
}

// ---------------------------------------------------------------------------
// k_mega (R12-verified): partB (1875 x 80 rows) U gemmA-L0 (125) U fill (313).
// ---------------------------------------------------------------------------
__global__ __launch_bounds__(512, 4) void k_mega(
    const float* __restrict__ edge_attr,
    const float* __restrict__ edge_w,
    const float* __restrict__ edge_b,
    const short* __restrict__ wt0,
    const short* __restrict__ wtl,
    const float* __restrict__ gcn0_b,
    const float* __restrict__ gcn_b,
    float* __restrict__ gpartB,
    unsigned short* __restrict__ hw0,
    const int* __restrict__ row,
    const int* __restrict__ col,
    int* __restrict__ cursor,
    const float* __restrict__ dinv,
    int2* __restrict__ edge_pack) {
    __shared__ short Hh[RBM * KS];   // 52480 B
    int bid = blockIdx.x, t = threadIdx.x;
    int lane = t & 63, w = t >> 6;
    int l16 = lane & 15, quad = lane >> 4;
    int nt0 = (w < 3) ? w * 3 : 9 + (w - 3) * 2;

    if (bid < PARTB_BLOCKS) {
        int base = N_NODES + bid * RBM;
        for (int i = t; i < RBM * 8; i += 512) {
            int r = i >> 3, c4 = (i & 7) * 4;
            const float* ar = edge_attr + (size_t)(base + r) * 3;
            float a0 = ar[0], a1 = ar[1], a2 = ar[2];
#pragma unroll
            for (int j = 0; j < 4; ++j) {
                int cc = c4 + j;
                float v = edge_b[cc];
                v = fmaf(a0, edge_w[cc], v);
                v = fmaf(a1, edge_w[32 + cc], v);
                v = fmaf(a2, edge_w[64 + cc], v);
                Hh[r * KS + cc] = bf16r(v);
            }
        }
        for (int i = t; i < RBM * 24; i += 512) {
            int r = i / 24, k = 304 + i % 24;
            Hh[r * KS + k] = 0;
        }
        __syncthreads();

        float* gout = gpartB + (size_t)bid * HIDP;
        if (w < 3) {
            f32x4 acc[5][3];
            kloop<5, 3>(wt0, 1, Hh, nt0, quad, l16, acc);
            __syncthreads();
            gcn_epilogue<5, 3>(gcn0_b, nt0, quad, l16, acc, Hh);
            __syncthreads();
            for (int l = 0; l < 4; ++l) {
                kloop<5, 3>(wtl + (size_t)l * 194560, 10, Hh, nt0, quad, l16, acc);
                __syncthreads();
                if (l < 3) {
                    gcn_epilogue<5, 3>(gcn_b + l * HID, nt0, quad, l16, acc, Hh);
                    __syncthreads();
                } else {
                    gcn_final<5, 3>(gcn_b + l * HID, nt0, quad, l16, acc, gout);
                }
            }
        } else {
            f32x4 acc[5][2];
            kloop<5, 2>(wt0, 1, Hh, nt0, quad, l16, acc);
            __syncthreads();
            gcn_epilogue<5, 2>(gcn0_b, nt0, quad, l16, acc, Hh);
            __syncthreads();
            for (int l = 0; l < 4; ++l) {
                kloop<5, 2>(wtl + (size_t)l * 194560, 10, Hh, nt0, quad, l16, acc);
                __syncthreads();
                if (l < 3) {
                    gcn_epilogue<5, 2>(gcn_b + l * HID, nt0, quad, l16, acc, Hh);
                    __syncthreads();
                } else {
                    gcn_final<5, 2>(gcn_b + l * HID, nt0, quad, l16, acc, gout);
                }
            }
        }
    } else if (bid < PARTB_BLOCKS + GEMMA_BLOCKS) {
        int base = (bid - PARTB_BLOCKS) * RBM;
        for (int i = t; i < RBM * 8; i += 512) {
            int r = i >> 3, c4 = (i & 7) * 4;
            const float* ar = edge_attr + (size_t)(base + r) * 3;
            float a0 = ar[0], a1 = ar[1], a2 = ar[2];
#pragma unroll
            for (int j = 0; j < 4; ++j) {
                int cc = c4 + j;
                float v = edge_b[cc];
                v = fmaf(a0, edge_w[cc], v);
                v = fmaf(a1, edge_w[32 + cc], v);
                v = fmaf(a2, edge_w[64 + cc], v);
                Hh[r * KS + cc] = bf16r(v);
            }
        }
        for (int i = t; i < RBM * 24; i += 512) {
            int r = i / 24, k = 304 + i % 24;
            Hh[r * KS + k] = 0;
        }
        __syncthreads();
        if (w < 3) {
            f32x4 acc[5][3];
            kloop<5, 3>(wt0, 1, Hh, nt0, quad, l16, acc);
            gemm_out<5, 3>(base, nt0, quad, l16, acc, hw0);
        } else {
            f32x4 acc[5][2];
            kloop<5, 2>(wt0, 1, Hh, nt0, quad, l16, acc);
            gemm_out<5, 2>(base, nt0, quad, l16, acc, hw0);
        }
    } else {
        int e = (bid - PARTB_BLOCKS - GEMMA_BLOCKS) * 512 + t;
        if (e < N_EDGES) {
            int c = col[e], r = row[e];
            int p = atomicAdd(&cursor[c], 1);
            edge_pack[p] = make_int2(r, __float_as_int(dinv[r] * dinv[c]));
        }
    }
}

// ---------------------------------------------------------------------------
// Vectorized agg: lane owns cols [4*lane .. 4*lane+3] (+tail 256+4*lane for
// lane<12). 2 ushort4 loads per edge row (was 5 scalar ushort) — 8 B/lane
// coalesced. Cols 300-303 stay self-consistently zero (zero-padded weights).
// ---------------------------------------------------------------------------
__device__ __forceinline__ void edge_acc(const unsigned short* __restrict__ h,
                                         float n, int lane,
                                         float (&a4)[4], float (&t4)[4]) {
    ushort4 m = *(const ushort4*)(h + 4 * lane);
    a4[0] = fmaf(n, b2f(m.x), a4[0]);
    a4[1] = fmaf(n, b2f(m.y), a4[1]);
    a4[2] = fmaf(n, b2f(m.z), a4[2]);
    a4[3] = fmaf(n, b2f(m.w), a4[3]);
    if (lane < 12) {
        ushort4 u = *(const ushort4*)(h + 256 + 4 * lane);
        t4[0] = fmaf(n, b2f(u.x), t4[0]);
        t4[1] = fmaf(n, b2f(u.y), t4[1]);
        t4[2] = fmaf(n, b2f(u.z), t4[2]);
        t4[3] = fmaf(n, b2f(u.w), t4[3]);
    }
}

__device__ __forceinline__ void agg_row_vec(int c, int lane,
                                            const unsigned short* __restrict__ hw_in,
                                            const int* __restrict__ col_start,
                                            const int2* __restrict__ edge_pack,
                                            float (&a4)[4], float (&t4)[4]) {
#pragma unroll
    for (int j = 0; j < 4; ++j) { a4[j] = 0.0f; t4[j] = 0.0f; }
    int beg = col_start[c], end = col_start[c + 1];
    int i = beg;
    for (; i + 4 <= end; i += 4) {
        int2 e0 = edge_pack[i], e1 = edge_pack[i + 1];
        int2 e2 = edge_pack[i + 2], e3 = edge_pack[i + 3];
        edge_acc(hw_in + (size_t)e0.x * HIDP, __int_as_float(e0.y), lane, a4, t4);
        edge_acc(hw_in + (size_t)e1.x * HIDP, __int_as_float(e1.y), lane, a4, t4);
        edge_acc(hw_in + (size_t)e2.x * HIDP, __int_as_float(e2.y), lane, a4, t4);
        edge_acc(hw_in + (size_t)e3.x * HIDP, __int_as_float(e3.y), lane, a4, t4);
    }
    for (; i < end; ++i) {
        int2 e0 = edge_pack[i];
        edge_acc(hw_in + (size_t)e0.x * HIDP, __int_as_float(e0.y), lane, a4, t4);
    }
}

// ---------------------------------------------------------------------------
// k_fuse: agg(prev hw) -> relu+bias -> LDS (ushort4 stores) -> gemm -> next hw
// ---------------------------------------------------------------------------
__global__ __launch_bounds__(512, 6) void k_fuse(
    const unsigned short* __restrict__ hw_in,
    const int* __restrict__ col_start,
    const int2* __restrict__ edge_pack,
    const float* __restrict__ selfnorm,
    const float* __restrict__ bias,
    const short* __restrict__ wt,
    unsigned short* __restrict__ hw_out) {
    __shared__ short Hh[RBF * KS];
    int t = threadIdx.x;
    int lane = t & 63, w = t >> 6;
    int l16 = lane & 15, quad = lane >> 4;
    int base = blockIdx.x * RBF;
    int nt0 = (w < 3) ? w * 3 : 9 + (w - 3) * 2;

#pragma unroll 1
    for (int j = 0; j < 4; ++j) {
        int r = w * 4 + j;
        int c = base + r;
        float a4[4], t4[4];
        if (c < N_NODES) {
            agg_row_vec(c, lane, hw_in, col_start, edge_pack, a4, t4);
            float sn = selfnorm[c];
            const unsigned short* sp = hw_in + (size_t)c * HIDP;
            // main cols 4*lane..4*lane+3
            {
                ushort4 sv = *(const ushort4*)(sp + 4 * lane);
                float b4[4] = {0.0f, 0.0f, 0.0f, 0.0f};
                if (lane < 75) {
                    float4 bb = *(const float4*)(bias + 4 * lane);
                    b4[0] = bb.x; b4[1] = bb.y; b4[2] = bb.z; b4[3] = bb.w;
                }
                float sf[4] = {b2f(sv.x), b2f(sv.y), b2f(sv.z), b2f(sv.w)};
                ushort4 o;
                o.x = (unsigned short)bf16r(fmaxf(a4[0] + sn * sf[0] + b4[0], 0.0f));
                o.y = (unsigned short)bf16r(fmaxf(a4[1] + sn * sf[1] + b4[1], 0.0f));
                o.z = (unsigned short)bf16r(fmaxf(a4[2] + sn * sf[2] + b4[2], 0.0f));
                o.w = (unsigned short)bf16r(fmaxf(a4[3] + sn * sf[3] + b4[3], 0.0f));
                *(ushort4*)&Hh[r * KS + 4 * lane] = o;
            }
            if (lane < 12) {
                ushort4 sv = *(const ushort4*)(sp + 256 + 4 * lane);
                float b4[4] = {0.0f, 0.0f, 0.0f, 0.0f};
                if (lane < 11) {
                    float4 bb = *(const float4*)(bias + 256 + 4 * lane);
                    b4[0] = bb.x; b4[1] = bb.y; b4[2] = bb.z; b4[3] = bb.w;
                }
                float sf[4] = {b2f(sv.x), b2f(sv.y), b2f(sv.z), b2f(sv.w)};
                ushort4 o;
                o.x = (unsigned short)bf16r(fmaxf(t4[0] + sn * sf[0] + b4[0], 0.0f));
                o.y = (unsigned short)bf16r(fmaxf(t4[1] + sn * sf[1] + b4[1], 0.0f));
                o.z = (unsigned short)bf16r(fmaxf(t4[2] + sn * sf[2] + b4[2], 0.0f));
                o.w = (unsigned short)bf16r(fmaxf(t4[3] + sn * sf[3] + b4[3], 0.0f));
                *(ushort4*)&Hh[r * KS + 256 + 4 * lane] = o;
            }
        } else {
            ushort4 z = make_ushort4(0, 0, 0, 0);
            *(ushort4*)&Hh[r * KS + 4 * lane] = z;
            if (lane < 12) *(ushort4*)&Hh[r * KS + 256 + 4 * lane] = z;
        }
    }
    for (int i = t; i < RBF * 24; i += 512) {
        int r = i / 24, k = 304 + i % 24;
        Hh[r * KS + k] = 0;
    }
    __syncthreads();

    if (w < 3) {
        f32x4 acc[2][3];
        kloop<2, 3>(wt, 10, Hh, nt0, quad, l16, acc);
        gemm_out<2, 3>(base, nt0, quad, l16, acc, hw_out);
    } else {
        f32x4 acc[2][2];
        kloop<2, 2>(wt, 10, Hh, nt0, quad, l16, acc);
        gemm_out<2, 2>(base, nt0, quad, l16, acc, hw_out);
    }
}

// ---------------------------------------------------------------------------
// k_last: final Part-A agg + colsum into g_sum (vectorized), with gpartB
// fold absorbed (waves 0..5 each add one gpartB row).
// ---------------------------------------------------------------------------
__global__ __launch_bounds__(512) void k_last(
    const unsigned short* __restrict__ hw_in,
    const int* __restrict__ col_start,
    const int2* __restrict__ edge_pack,
    const float* __restrict__ selfnorm,
    const float* __restrict__ bias,
    const float* __restrict__ gpartB,
    float* __restrict__ g_sum) {
    __shared__ float red[8 * 320];
    int t = threadIdx.x;
    int lane = t & 63, w = t >> 6;
    int base = blockIdx.x * RBF;

    float sa[4] = {0.0f, 0.0f, 0.0f, 0.0f};
    float st[4] = {0.0f, 0.0f, 0.0f, 0.0f};
#pragma unroll 1
    for (int j = 0; j < 4; ++j) {
        int c = base + w * 4 + j;
        if (c < N_NODES) {
            float a4[4], t4[4];
            agg_row_vec(c, lane, hw_in, col_start, edge_pack, a4, t4);
            float sn = selfnorm[c];
            const unsigned short* sp = hw_in + (size_t)c * HIDP;
            {
                ushort4 sv = *(const ushort4*)(sp + 4 * lane);
                float b4[4] = {0.0f, 0.0f, 0.0f, 0.0f};
                if (lane < 75) {
                    float4 bb = *(const float4*)(bias + 4 * lane);
                    b4[0] = bb.x; b4[1] = bb.y; b4[2] = bb.z; b4[3] = bb.w;
                }
                float sf[4] = {b2f(sv.x), b2f(sv.y), b2f(sv.z), b2f(sv.w)};
#pragma unroll
                for (int q = 0; q < 4; ++q) {
                    float hv = a4[q] + sn * sf[q] + b4[q];
                    // cols 300-303 are exactly 0 (zero weights) -> relu(0)=0 safe
                    sa[q] += fmaxf(hv, 0.0f);
                }
            }
            if (lane < 12) {
                ushort4 sv = *(const ushort4*)(sp + 256 + 4 * lane);
                float b4[4] = {0.0f, 0.0f, 0.0f, 0.0f};
                if (lane < 11) {
                    float4 bb = *(const float4*)(bias + 256 + 4 * lane);
                    b4[0] = bb.x; b4[1] = bb.y; b4[2] = bb.z; b4[3] = bb.w;
                }
                float sf[4] = {b2f(sv.x), b2f(sv.y), b2f(sv.z), b2f(sv.w)};
#pragma unroll
                for (int q = 0; q < 4; ++q) {
                    float hv = t4[q] + sn * sf[q] + b4[q];
                    st[q] += fmaxf(hv, 0.0f);
                }
            }
        }
    }
    // fold partB per-block partials (6 rows per block; 313*6 >= 1875)
    if (w < 6) {
        int rr = blockIdx.x * 6 + w;
        if (rr < PARTB_BLOCKS) {
            const float* gp = gpartB + (size_t)rr * HIDP;
            float4 gv = *(const float4*)(gp + 4 * lane);
            sa[0] += gv.x; sa[1] += gv.y; sa[2] += gv.z; sa[3] += gv.w;
            if (lane < 12) {
                float4 gu = *(const float4*)(gp + 256 + 4 * lane);
                st[0] += gu.x; st[1] += gu.y; st[2] += gu.z; st[3] += gu.w;
            }
        }
    }
#pragma unroll
    for (int q = 0; q < 4; ++q) red[w * 320 + 4 * lane + q] = sa[q];
    if (lane < 12)
#pragma unroll
        for (int q = 0; q < 4; ++q) red[w * 320 + 256 + 4 * lane + q] = st[q];
    __syncthreads();
    if (w == 0) {
#pragma unroll
        for (int q = 0; q < 4; ++q) {
            int cc = 4 * lane + q;
            float tot = 0.0f;
#pragma unroll
            for (int g = 0; g < 8; ++g) tot += red[g * 320 + cc];
            if (cc < HID) atomicAdd(&g_sum[cc], tot);
        }
        if (lane < 12) {
#pragma unroll
            for (int q = 0; q < 4; ++q) {
                int cc = 256 + 4 * lane + q;
                float tot = 0.0f;
#pragma unroll
                for (int g = 0; g < 8; ++g) tot += red[g * 320 + cc];
                if (cc < HID) atomicAdd(&g_sum[cc], tot);
            }
        }
    }
}

__global__ void k_head(const float* __restrict__ g_sum,
                       const float* __restrict__ lin1_w, const float* __restrict__ lin1_b,
                       const float* __restrict__ lin2_w, const float* __restrict__ lin2_b,
                       float* __restrict__ out) {
    __shared__ float g2[32];
    int t = threadIdx.x;
    const float inv = 1.0f / (float)N_EDGES;
    if (t < 32) {
        float a = lin1_b[t];
        for (int d = 0; d < HID; ++d) a = fmaf(g_sum[d] * inv, lin1_w[d * 32 + t], a);
        g2[t] = fmaxf(a, 0.0f);
    }
    __syncthreads();
    if (t < 2) {
        float p = lin2_b[t];
        for (int j = 0; j < 32; ++j) p = fmaf(g2[j], lin2_w[j * 2 + t], p);
        out[t] = p;
    }
}

// ---------------------------------------------------------------------------

extern "C" void kernel_launch(void* const* d_in, const int* in_sizes, int n_in,
                              void* d_out, int out_size, void* d_ws, size_t ws_size,
                              hipStream_t stream) {
    (void)in_sizes; (void)n_in; (void)out_size; (void)ws_size;
    const int* edge_index = (const int*)d_in[1];
    const float* edge_attr = (const float*)d_in[2];
    const float* edge_w = (const float*)d_in[6];
    const float* edge_b = (const float*)d_in[7];
    const float* gcn0_w = (const float*)d_in[8];
    const float* gcn0_b = (const float*)d_in[9];
    const float* gcn_w = (const float*)d_in[10];
    const float* gcn_b = (const float*)d_in[11];
    const float* lin1_w = (const float*)d_in[12];
    const float* lin1_b = (const float*)d_in[13];
    const float* lin2_w = (const float*)d_in[14];
    const float* lin2_b = (const float*)d_in[15];

    char* ws = (char*)d_ws;
    size_t off = 0;
    auto alloc = [&](size_t bytes) {
        void* p = ws + off;
        off = (off + bytes + 255) & ~(size_t)255;
        return p;
    };
    unsigned short* hwA = (unsigned short*)alloc((size_t)N_NODES * HIDP * 2);
    unsigned short* hwB = (unsigned short*)alloc((size_t)N_NODES * HIDP * 2);
    int2* edge_pack = (int2*)alloc((size_t)N_EDGES * 8);
    int* cnt = (int*)alloc((size_t)N_NODES * 4);
    int* col_start = (int*)alloc((size_t)(N_NODES + 1) * 4);
    int* cursor = (int*)alloc((size_t)N_NODES * 4);
    float* dinv = (float*)alloc((size_t)N_NODES * 4);
    float* selfnorm = (float*)alloc((size_t)N_NODES * 4);
    float* g_sum = (float*)alloc((size_t)HIDP * 4);
    short* wt0 = (short*)alloc((size_t)38912);
    short* wtl = (short*)alloc((size_t)4 * 389120);
    float* gpartB = (float*)alloc((size_t)PARTB_BLOCKS * HIDP * 4);

    const int* row = edge_index;
    const int* col = edge_index + N_EDGES;

    hipMemsetAsync(cnt, 0, N_NODES * 4, stream);
    hipMemsetAsync(g_sum, 0, HIDP * 4, stream);

    k_prep<<<(N_EDGES + 255) / 256, 256, 0, stream>>>(gcn0_w, gcn_w, wt0, wtl, col, cnt);
    k_scan<<<1, 1024, 0, stream>>>(cnt, col_start, cursor, dinv, selfnorm);

    // mega: partB (80-row blocks) + Part-A L0 + CSR fill (R12-verified, 199 us)
    k_mega<<<MEGA_BLOCKS, 512, 0, stream>>>(edge_attr, edge_w, edge_b, wt0, wtl,
                                            gcn0_b, gcn_b, gpartB, hwA,
                                            row, col, cursor, dinv, edge_pack);

    // Part A layers 1..4: fused agg+gemm per layer (vectorized agg)
    k_fuse<<<FUSE_BLOCKS, 512, 0, stream>>>(hwA, col_start, edge_pack, selfnorm,
                                            gcn0_b, wtl + (size_t)0 * 194560, hwB);
    k_fuse<<<FUSE_BLOCKS, 512, 0, stream>>>(hwB, col_start, edge_pack, selfnorm,
                                            gcn_b + 0 * HID, wtl + (size_t)1 * 194560, hwA);
    k_fuse<<<FUSE_BLOCKS, 512, 0, stream>>>(hwA, col_start, edge_pack, selfnorm,
                                            gcn_b + 1 * HID, wtl + (size_t)2 * 194560, hwB);
    k_fuse<<<FUSE_BLOCKS, 512, 0, stream>>>(hwB, col_start, edge_pack, selfnorm,
                                            gcn_b + 2 * HID, wtl + (size_t)3 * 194560, hwA);
    // final agg + colsum + partB fold, then head
    k_last<<<FUSE_BLOCKS, 512, 0, stream>>>(hwA, col_start, edge_pack, selfnorm,
                                            gcn_b + 3 * HID, gpartB, g_sum);
    k_head<<<1, 64, 0, stream>>>(g_sum, lin1_w, lin1_b, lin2_w, lin2_b, (float*)d_out);
}